// Round 12
// baseline (1548.050 us; speedup 1.0000x reference)
//
#include <hip/hip_runtime.h>
#include <cstdint>
#include <cstddef>

typedef _Float16 half8 __attribute__((ext_vector_type(8)));
typedef _Float16 half4 __attribute__((ext_vector_type(4)));
typedef float floatx4 __attribute__((ext_vector_type(4)));

namespace {
constexpr int kB = 256, kT = 512, kIN = 48, kOUT = 48, kSEAS = 24, kH = 128;
constexpr int kW = kT - kIN + 1;           // 465 windows
constexpr int kWO = kT - kOUT - kIN + 1;   // 417
constexpr int kNB = kW * kB;               // 119040 rows
constexpr int kMBLK = kNB / 16;            // 7440 row-blocks of 16
constexpr float kLOG2E = 1.44269504088896340736f;
constexpr int kWOBLK = (kWO * kB * 12 + 255) / 256;  // win_out grid chunk
}

#if __has_builtin(__builtin_amdgcn_exp2f)
#define FEXP2(x) __builtin_amdgcn_exp2f(x)
#else
#define FEXP2(x) exp2f(x)
#endif
#if __has_builtin(__builtin_amdgcn_rcpf)
#define FRCP(x) __builtin_amdgcn_rcpf(x)
#else
#define FRCP(x) (1.0f / (x))
#endif

// LDS-only barrier: does NOT drain vmcnt
#define LGKM_BARRIER() asm volatile("s_waitcnt lgkmcnt(0)\n\ts_barrier" ::: "memory")

__device__ __forceinline__ float fsig(float y) { return FRCP(1.0f + FEXP2(-y)); }
__device__ __forceinline__ float ftanh(float x) { return 2.0f * fsig(2.0f * kLOG2E * x) - 1.0f; }

// ---------------- ES scan, BLOCKED lag-24; reads train directly ----------------
template <int N>
__device__ __forceinline__ void es_block(int k0, int b, float lev_sm, float omb_l,
                                         float seas_sm, float omb_s, float& lev,
                                         float (&stprev)[kSEAS], const float* __restrict__ trow,
                                         float* __restrict__ seas, float* __restrict__ levs,
                                         float* __restrict__ ratio) {
  float x[N], q[N], lv[N];
#pragma unroll
  for (int jj = 0; jj < N; ++jj) x[jj] = trow[k0 + jj + 1];
#pragma unroll
  for (int jj = 0; jj < N; ++jj) q[jj] = x[jj] * FRCP(stprev[jj]);  // pipelined rcps
#pragma unroll
  for (int jj = 0; jj < N; ++jj) {  // only serial chain: 1 fma per step
    lev = lev_sm * q[jj] + omb_l * lev;
    lv[jj] = lev;
  }
#pragma unroll
  for (int jj = 0; jj < N; ++jj) {
    float sn = seas_sm * (x[jj] * FRCP(lv[jj])) + omb_s * stprev[jj];
    stprev[jj] = sn;
    seas[(k0 + jj + kSEAS + 1) * kB + b] = sn;
    levs[(k0 + jj + 1) * kB + b] = lv[jj];
    ratio[(k0 + jj + 1) * kB + b] = q[jj];
  }
}

__global__ void k_es(const float* __restrict__ train, const float* __restrict__ levp,
                     const float* __restrict__ seasp, const float* __restrict__ inits,
                     float* __restrict__ seas, float* __restrict__ levs,
                     float* __restrict__ ratio) {
  int b = threadIdx.x;
  const float* trow = train + (size_t)b * kT;
  float lev_sm = fsig(levp[0] * kLOG2E);
  float seas_sm = fsig(seasp[0] * kLOG2E);
  float omb_l = 1.0f - lev_sm, omb_s = 1.0f - seas_sm;
  float stprev[kSEAS];
  float s00 = expf(inits[0]);
#pragma unroll
  for (int s = 0; s < kSEAS; ++s) {
    float v = expf(inits[s]);
    seas[s * kB + b] = v;
    if (s >= 1) stprev[s - 1] = v;
  }
  stprev[kSEAS - 1] = s00;
  seas[kSEAS * kB + b] = s00;
  float lev = trow[0] * FRCP(s00);
  levs[b] = lev;
  ratio[b] = lev;
#pragma unroll 1
  for (int blk = 0; blk < 21; ++blk)
    es_block<24>(blk * kSEAS, b, lev_sm, omb_l, seas_sm, omb_s, lev, stprev, trow, seas, levs,
                 ratio);
  es_block<7>(504, b, lev_sm, omb_l, seas_sm, omb_s, lev, stprev, trow, seas, levs, ratio);
  for (int j = 0; j < kOUT - kSEAS; ++j)
    seas[(kT + kSEAS + j) * kB + b] = seas[(kT + j) * kB + b];
}

// ---------------- window build: win_in + win_out in one kernel ----------------
__global__ void k_win(const float* __restrict__ ratio, const float* __restrict__ levs,
                      _Float16* __restrict__ win, float* __restrict__ out1) {
  int w = blockIdx.x;
  int tid = threadIdx.x;
  if (w < kW) {  // win_in: f16, padded K=64
#pragma unroll
    for (int i = 0; i < 16; ++i) {
      int o = i * 256 + tid;
      int b = o >> 3;
      int j0 = (o & 7) * 8;
      half8 h;
      if (j0 < kIN) {
        float rl = FRCP(levs[(kIN - 1 + w) * kB + b]);
#pragma unroll
        for (int jj = 0; jj < 8; ++jj) {
          int j = j0 + jj;
          float v = (j < kIN) ? ratio[(w + j) * kB + b] * rl : 0.0f;
          h[jj] = (_Float16)v;
        }
      } else {
#pragma unroll
        for (int jj = 0; jj < 8; ++jj) h[jj] = (_Float16)0.0f;
      }
      *(half8*)(win + ((size_t)(w * kB + b)) * 64 + j0) = h;
    }
  } else {  // win_out -> out1 (fp32 exact)
    int idx = (w - kW) * 256 + tid;
    if (idx >= kWO * kB * 12) return;
    int row = idx / 12;
    int j0 = (idx - row * 12) * 4;
    int wo = row >> 8;
    int b = row & 255;
    float rl = FRCP(levs[(kIN - 1 + wo) * kB + b]);
    floatx4 v;
#pragma unroll
    for (int jj = 0; jj < 4; ++jj) v[jj] = ratio[(kIN + wo + j0 + jj) * kB + b] * rl;
    *(floatx4*)(out1 + (size_t)row * kOUT + j0) = v;
  }
}

// ---------------- weight prep (single kernel, blockIdx.y = segment; seg14 zeros prog) ----------------
__device__ __forceinline__ void prep_bias_elem(const float* bih, const float* bhh, float* dst,
                                               int c) {
  int ct = c >> 4, n16 = c & 15, g = ct & 3, wv = ct >> 2;
  int row = g * 128 + wv * 16 + n16;
  float sc = (g == 2) ? 2.0f * kLOG2E : kLOG2E;
  dst[c] = (bih[row] + bhh[row]) * sc;
}

__device__ __forceinline__ void prep_frag_elem(const float* Wsrc, _Float16* dst, int KB, int Kreal,
                                               int srcld, int perm, int idx) {
  int jj = idx & 7;
  int lane = (idx >> 3) & 63;
  int kb = (idx >> 9) % KB;
  int ct = idx / (KB * 512);
  int n16 = lane & 15;
  int k = kb * 32 + ((lane >> 4) << 3) + jj;
  int row;
  float sc;
  if (perm) {
    int g = ct & 3, wv = ct >> 2;
    row = g * 128 + wv * 16 + n16;
    sc = (g == 2) ? 2.0f * kLOG2E : kLOG2E;
  } else {
    row = ct * 16 + n16;
    sc = 1.0f;
  }
  float v = (k < Kreal) ? Wsrc[row * srcld + k] * sc : 0.0f;
  dst[idx] = (_Float16)v;
}

struct PrepArgs {
  const float* bih[4];
  const float* bhh[4];
  float* biasp[4];
  const float* wih[4];
  _Float16* wihf[4];
  const float* whh[4];
  _Float16* whhf[4];
  const float* nlw;
  _Float16* nlf;
  const float* scw;
  _Float16* scf;
  int* prog;
};

__global__ void k_prep_all(PrepArgs a) {
  int seg = blockIdx.y;
  int idx = blockIdx.x * 256 + threadIdx.x;
  if (seg < 4) {
    if (idx < 512) prep_bias_elem(a.bih[seg], a.bhh[seg], a.biasp[seg], idx);
  } else if (seg == 4) {
    if (idx < 32 * 2 * 512) prep_frag_elem(a.wih[0], a.wihf[0], 2, 48, 48, 1, idx);
  } else if (seg < 8) {
    int c = seg - 4;
    if (idx < 32 * 4 * 512) prep_frag_elem(a.wih[c], a.wihf[c], 4, 128, 128, 1, idx);
  } else if (seg < 12) {
    int c = seg - 8;
    if (idx < 32 * 4 * 512) prep_frag_elem(a.whh[c], a.whhf[c], 4, 128, 128, 1, idx);
  } else if (seg == 12) {
    if (idx < 8 * 4 * 512) prep_frag_elem(a.nlw, a.nlf, 4, 128, 128, 0, idx);
  } else if (seg == 13) {
    if (idx < 3 * 4 * 512) prep_frag_elem(a.scw, a.scf, 4, 128, 128, 0, idx);
  } else {
    if (idx < 320) a.prog[idx] = 0;
  }
}

// ---------------- fused 4-cell streaming LSTM + streaming nl/sc tail WGs ----------------
// 256 WGs: cell0=wg[0,16) d=1; cell1=[16,48) d=2; cell2=[48,112) d=4; cell3=[112,240) d=8
// (cell3 releases prog[192+ib*8+kd], quantum 2); tail=wg[240,256): per ib, consumes H3/H1
// row-blocks as released, U=tanh((H3+H1)@nl^T+nl_b) in-register, out3/out0 = U@sc^T+sc_b.
struct FArgs {
  const _Float16* win;
  const _Float16* wihf[4];
  const _Float16* whhf[4];
  const float* biasp[4];
  _Float16* H[4];
  int* prog;
  const _Float16* nlf;
  const _Float16* scf;
  const float* nlb;
  const float* scb;
  float* out3;
  float* out0;
};

__device__ __forceinline__ void wait_prog(int* p, int need, int& fenced, int* obs_sh) {
  if (need <= fenced) return;  // uniform condition
  if (threadIdx.x == 0) {
    int v;
    while ((v = __hip_atomic_load(p, __ATOMIC_RELAXED, __HIP_MEMORY_SCOPE_AGENT)) < need)
      __builtin_amdgcn_s_sleep(16);
    *obs_sh = v;
  }
  __syncthreads();
  int v = *obs_sh;
  __builtin_amdgcn_fence(__ATOMIC_ACQUIRE, "agent");  // single buffer_inv
  fenced = v;
}

template <int KXB, bool POLL, bool REL, int RELMASK>
__device__ __forceinline__ void floop(const _Float16* __restrict__ Xsrc,
                                      const _Float16* __restrict__ wihp,
                                      const _Float16* __restrict__ whhp,
                                      const float* __restrict__ bp, _Float16* __restrict__ Hout,
                                      int* progIn, int sprev, int* progOut, int d, int kd, int ib,
                                      _Float16 (*hbuf)[2048], int* obs_sh) {
  int tid = threadIdx.x;
  int wv = tid >> 6, lane = tid & 63, m = lane & 15, kq = lane >> 4;
  half8 wxf[4][KXB], whf[4][4];
#pragma unroll
  for (int g = 0; g < 4; ++g) {
#pragma unroll
    for (int kb = 0; kb < KXB; ++kb)
      wxf[g][kb] = *(const half8*)(wihp + ((((wv * 4 + g) * KXB + kb) * 64 + lane) * 8));
#pragma unroll
    for (int kb = 0; kb < 4; ++kb)
      whf[g][kb] = *(const half8*)(whhp + ((((wv * 4 + g) * 4 + kb) * 64 + lane) * 8));
  }
  float bg[4];
#pragma unroll
  for (int g = 0; g < 4; ++g) bg[g] = bp[(wv * 4 + g) * 16 + m];
  float cc[4] = {0.f, 0.f, 0.f, 0.f};
  int nsteps = (kW - kd + d - 1) / d;
  const int xstride = KXB * 32;
  int fenced = 0;
  if (POLL) wait_prog(progIn + (kd & ((1 << sprev) - 1)), (kd >> sprev) + 1, fenced, obs_sh);
  half8 hxc[KXB], hxn[KXB];
  {
    const _Float16* xrow = Xsrc + (size_t)(kd * kB + ib * 16 + m) * xstride + kq * 8;
#pragma unroll
    for (int kb = 0; kb < KXB; ++kb) hxc[kb] = *(const half8*)(xrow + kb * 32);
  }
  for (int j = 0; j < nsteps; ++j) {
    int ph = j & 1;
    int wtn = (j + 1) * d + kd;
    bool havenext = (j + 1 < nsteps);
    if (POLL && havenext)
      wait_prog(progIn + (wtn & ((1 << sprev) - 1)), (wtn >> sprev) + 1, fenced, obs_sh);
    floatx4 acc[4];
#pragma unroll
    for (int g = 0; g < 4; ++g) acc[g] = (floatx4){bg[g], bg[g], bg[g], bg[g]};
    if (havenext) {
      const _Float16* xrow = Xsrc + (size_t)(wtn * kB + ib * 16 + m) * xstride + kq * 8;
#pragma unroll
      for (int kb = 0; kb < KXB; ++kb) hxn[kb] = *(const half8*)(xrow + kb * 32);
    }
#pragma unroll
    for (int kb = 0; kb < KXB; ++kb)
#pragma unroll
      for (int g = 0; g < 4; ++g)
        acc[g] = __builtin_amdgcn_mfma_f32_16x16x32_f16(hxc[kb], wxf[g][kb], acc[g], 0, 0, 0);
    if (j > 0) {
#pragma unroll
      for (int kb = 0; kb < 4; ++kb) {
        int gran = (kb * 4 + kq) ^ m;
        half8 a = *(const half8*)(&hbuf[ph ^ 1][m * 128 + gran * 8]);
#pragma unroll
        for (int g = 0; g < 4; ++g)
          acc[g] = __builtin_amdgcn_mfma_f32_16x16x32_f16(a, whf[g][kb], acc[g], 0, 0, 0);
      }
    }
    _Float16 hv[4];
#pragma unroll
    for (int r = 0; r < 4; ++r) {
      float iv = fsig(acc[0][r]);
      float fv = fsig(acc[1][r]);
      float g2 = fsig(acc[2][r]);
      float ov = fsig(acc[3][r]);
      cc[r] = fv * cc[r] + iv * (2.0f * g2 - 1.0f);
      float tc = 2.0f * fsig(cc[r] * (2.0f * kLOG2E)) - 1.0f;
      hv[r] = (_Float16)(ov * tc);
      int brow = kq * 4 + r;
      int hu = wv * 16 + m;
      int gran = (hu >> 3) ^ brow;
      hbuf[ph][brow * 128 + gran * 8 + (hu & 7)] = hv[r];
    }
    __syncthreads();
    {
      int hu = wv * 16 + m;
      size_t rb = (size_t)((j * d + kd) * kB + ib * 16 + kq * 4);
#pragma unroll
      for (int r = 0; r < 4; ++r) Hout[(rb + r) * kH + hu] = hv[r];
    }
    if (REL && (((j & RELMASK) == RELMASK) || (j + 1 == nsteps))) {
      __syncthreads();  // full drain (vmcnt0): H stores visible before release
      if (tid == 0)
        __hip_atomic_store(progOut, j + 1, __ATOMIC_RELEASE, __HIP_MEMORY_SCOPE_AGENT);
    }
#pragma unroll
    for (int kb = 0; kb < KXB; ++kb) hxc[kb] = hxn[kb];
  }
}

// Tail WG: stream nl+sc epilogue for chains of batch-block ib.
// DEADLOCK FIX (R11): only wait on producer chains that actually own a row in
// [t0, tend) — the ragged final block must not demand progress past a chain's end.
__device__ void tail_loop(const FArgs& a, int ib, _Float16 (*hbuf)[2048]) {
  int tid = threadIdx.x;
  int wv = tid >> 6, lane = tid & 63, m = lane & 15, kq = lane >> 4;
  half8 nf[4], sf[4];
  int cts = (wv < 3) ? wv : 0;
#pragma unroll
  for (int kb = 0; kb < 4; ++kb) {
    nf[kb] = *(const half8*)(a.nlf + ((size_t)((wv * 4 + kb) * 64 + lane)) * 8);
    sf[kb] = *(const half8*)(a.scf + ((size_t)((cts * 4 + kb) * 64 + lane)) * 8);
  }
  float nb = a.nlb[wv * 16 + m];
  float sb = (wv < 3) ? a.scb[wv * 16 + m] : 0.0f;
  int* prog3 = a.prog + 192 + ib * 8;
  int* prog1 = a.prog + (16 + ib) * 4;
  const _Float16* H3 = a.H[3];
  const _Float16* H1 = a.H[1];
  for (int t0 = 0; t0 < kW; t0 += 8) {
    int tend = (t0 + 8 < kW) ? t0 + 8 : kW;
    if (tid == 0) {
      // cell3: chain kd owns row t0+kd (j = t0>>3) — only if that row exists
      int need3 = (t0 >> 3) + 1;
      for (int kd = 0; kd < 8; ++kd) {
        if (t0 + kd >= tend) break;
        while (__hip_atomic_load(prog3 + kd, __ATOMIC_RELAXED, __HIP_MEMORY_SCOPE_AGENT) < need3)
          __builtin_amdgcn_s_sleep(16);
      }
      // cell1: chain kd (parity) — largest row of that parity in [t0, tend)
      for (int kd = 0; kd < 2; ++kd) {
        int tmaxk = tend - 1;
        if ((tmaxk & 1) != kd) --tmaxk;
        if (tmaxk < t0) continue;
        int need1 = (tmaxk >> 1) + 1;
        while (__hip_atomic_load(prog1 + kd, __ATOMIC_RELAXED, __HIP_MEMORY_SCOPE_AGENT) < need1)
          __builtin_amdgcn_s_sleep(16);
      }
    }
    __syncthreads();
    __builtin_amdgcn_fence(__ATOMIC_ACQUIRE, "agent");
#pragma unroll 1
    for (int t = t0; t < tend; ++t) {
      int ph = t & 1;
      const _Float16* r3 = H3 + (size_t)(t * kB + ib * 16 + m) * kH + kq * 8;
      const _Float16* r1 = H1 + (size_t)(t * kB + ib * 16 + m) * kH + kq * 8;
      half8 af[4];
#pragma unroll
      for (int kb = 0; kb < 4; ++kb) {
        half8 v3 = *(const half8*)(r3 + kb * 32);
        half8 v1 = *(const half8*)(r1 + kb * 32);
        af[kb] = v3 + v1;
      }
      floatx4 acc = {nb, nb, nb, nb};
#pragma unroll
      for (int kb = 0; kb < 4; ++kb)
        acc = __builtin_amdgcn_mfma_f32_16x16x32_f16(af[kb], nf[kb], acc, 0, 0, 0);
#pragma unroll
      for (int r = 0; r < 4; ++r) {  // U tile -> swizzled LDS
        _Float16 uv = (_Float16)ftanh(acc[r]);
        int brow = kq * 4 + r;
        int hu = wv * 16 + m;
        int gran = (hu >> 3) ^ brow;
        hbuf[ph][brow * 128 + gran * 8 + (hu & 7)] = uv;
      }
      LGKM_BARRIER();
      if (wv < 3) {  // sc: 3 ctiles of 16 cols each
        half8 uf[4];
#pragma unroll
        for (int kb = 0; kb < 4; ++kb) {
          int gran = (kb * 4 + kq) ^ m;
          uf[kb] = *(const half8*)(&hbuf[ph][m * 128 + gran * 8]);
        }
        floatx4 a2 = {sb, sb, sb, sb};
#pragma unroll
        for (int kb = 0; kb < 4; ++kb)
          a2 = __builtin_amdgcn_mfma_f32_16x16x32_f16(uf[kb], sf[kb], a2, 0, 0, 0);
        size_t row = (size_t)t * kB + ib * 16 + kq * 4;
        bool dup = (t < kWO);
#pragma unroll
        for (int r = 0; r < 4; ++r) {
          float v = a2[r];
          a.out3[(row + r) * kOUT + wv * 16 + m] = v;
          if (dup) a.out0[(row + r) * kOUT + wv * 16 + m] = v;
        }
      }
    }
  }
}

__global__ __launch_bounds__(512) void k_fused(FArgs a) {
  __shared__ _Float16 hbuf[2][2048];
  __shared__ int obs_sh;
  int w = blockIdx.x;
  if (w >= 240) {  // tail WG: streaming nl+sc epilogue (same XCD as its producers)
    tail_loop(a, w - 240, hbuf);
    return;
  }
  int cell, d, kd, ib;
  if (w < 16) {
    cell = 0; d = 1; kd = 0; ib = w;
  } else if (w < 48) {
    cell = 1; d = 2; kd = (w - 16) >> 4; ib = (w - 16) & 15;
  } else if (w < 112) {
    cell = 2; d = 4; kd = (w - 48) >> 4; ib = (w - 48) & 15;
  } else {
    cell = 3; d = 8; kd = (w - 112) >> 4; ib = (w - 112) & 15;
  }
  const _Float16* Xsrc = (cell == 0) ? a.win : a.H[cell - 1];
  _Float16* Hout = a.H[cell];
  int* progOut = (cell == 3) ? a.prog + 192 + ib * 8 + kd : a.prog + (cell * 16 + ib) * 4 + kd;
  int* progIn = (cell > 0) ? a.prog + ((cell - 1) * 16 + ib) * 4 : nullptr;
  int sprev = (cell == 2) ? 1 : ((cell == 3) ? 2 : 0);
  if (cell == 0)
    floop<2, false, true, 7>(Xsrc, a.wihf[0], a.whhf[0], a.biasp[0], Hout, nullptr, 0, progOut,
                             d, kd, ib, hbuf, &obs_sh);
  else if (cell < 3)
    floop<4, true, true, 7>(Xsrc, a.wihf[cell], a.whhf[cell], a.biasp[cell], Hout, progIn,
                            sprev, progOut, d, kd, ib, hbuf, &obs_sh);
  else
    floop<4, true, true, 1>(Xsrc, a.wihf[3], a.whhf[3], a.biasp[3], Hout, progIn, sprev,
                            progOut, d, kd, ib, hbuf, &obs_sh);
}

// ---------------- tail: outputs 2, 4, 5 ----------------
__global__ void k_tail(const float* __restrict__ out3, const float* __restrict__ val,
                       const float* __restrict__ seas, const float* __restrict__ levs,
                       float* __restrict__ out2, float* __restrict__ out4,
                       float* __restrict__ out5) {
  int idx = blockIdx.x * 256 + threadIdx.x;
  int b = idx / kOUT, j = idx % kOUT;
  float s = seas[(kT + j) * kB + b];
  float L = levs[(kT - 1) * kB + b];
  float net = out3[(size_t)(kW - 1) * kB * kOUT + idx];
  float hp = net * s * L;
  out2[idx] = hp > 0.0f ? hp : 0.0f;
  float v = val[idx];
  out4[idx] = v;
  out5[idx] = v / s / L;
}

extern "C" void kernel_launch(void* const* d_in, const int* in_sizes, int n_in, void* d_out,
                              int out_size, void* d_ws, size_t ws_size, hipStream_t stream) {
  const float* train = (const float*)d_in[0];
  const float* val = (const float*)d_in[1];
  const float* levp = (const float*)d_in[3];
  const float* seasp = (const float*)d_in[4];
  const float* inits = (const float*)d_in[5];
  const float* w_ih[4] = {(const float*)d_in[6], (const float*)d_in[10], (const float*)d_in[14],
                          (const float*)d_in[18]};
  const float* w_hh[4] = {(const float*)d_in[7], (const float*)d_in[11], (const float*)d_in[15],
                          (const float*)d_in[19]};
  const float* b_ih[4] = {(const float*)d_in[8], (const float*)d_in[12], (const float*)d_in[16],
                          (const float*)d_in[20]};
  const float* b_hh[4] = {(const float*)d_in[9], (const float*)d_in[13], (const float*)d_in[17],
                          (const float*)d_in[21]};
  const float* nl_w = (const float*)d_in[22];
  const float* nl_b = (const float*)d_in[23];
  const float* sc_w = (const float*)d_in[24];
  const float* sc_b = (const float*)d_in[25];

  char* wsb = (char*)d_ws;
  size_t off = 0;
  auto alloc = [&](size_t bytes) -> void* {
    void* p = wsb + off;
    off = (off + bytes + 255) & ~(size_t)255;
    return p;
  };
  float* seas = (float*)alloc((size_t)560 * kB * 4);
  float* levs = (float*)alloc((size_t)kT * kB * 4);
  float* ratio = (float*)alloc((size_t)kT * kB * 4);
  _Float16* win = (_Float16*)alloc((size_t)kNB * 64 * 2);
  _Float16* Hc[4];
  for (int c = 0; c < 4; ++c) Hc[c] = (_Float16*)alloc((size_t)kNB * kH * 2);
  float* biasp[4];
  for (int c = 0; c < 4; ++c) biasp[c] = (float*)alloc(512 * 4);
  _Float16* wihf[4];
  wihf[0] = (_Float16*)alloc((size_t)32 * 2 * 512 * 2);
  for (int c = 1; c < 4; ++c) wihf[c] = (_Float16*)alloc((size_t)32 * 4 * 512 * 2);
  _Float16* whhf[4];
  for (int c = 0; c < 4; ++c) whhf[c] = (_Float16*)alloc((size_t)32 * 4 * 512 * 2);
  _Float16* nlf = (_Float16*)alloc((size_t)8 * 4 * 512 * 2);
  _Float16* scf = (_Float16*)alloc((size_t)3 * 4 * 512 * 2);
  int* prog = (int*)alloc(320 * 4);

  float* out0 = (float*)d_out;
  float* out1 = out0 + (size_t)kWO * kB * kOUT;
  float* out2 = out1 + (size_t)kWO * kB * kOUT;
  float* out3 = out2 + (size_t)kB * kOUT;
  float* out4 = out3 + (size_t)kW * kB * kOUT;
  float* out5 = out4 + (size_t)kB * kOUT;

  k_es<<<1, kB, 0, stream>>>(train, levp, seasp, inits, seas, levs, ratio);
  k_win<<<kW + kWOBLK, kB, 0, stream>>>(ratio, levs, win, out1);

  PrepArgs pa;
  for (int c = 0; c < 4; ++c) {
    pa.bih[c] = b_ih[c]; pa.bhh[c] = b_hh[c]; pa.biasp[c] = biasp[c];
    pa.wih[c] = w_ih[c]; pa.wihf[c] = wihf[c];
    pa.whh[c] = w_hh[c]; pa.whhf[c] = whhf[c];
  }
  pa.nlw = nl_w; pa.nlf = nlf; pa.scw = sc_w; pa.scf = scf; pa.prog = prog;
  k_prep_all<<<dim3(256, 15), 256, 0, stream>>>(pa);

  FArgs fa;
  fa.win = win;
  for (int c = 0; c < 4; ++c) {
    fa.wihf[c] = wihf[c]; fa.whhf[c] = whhf[c]; fa.biasp[c] = biasp[c]; fa.H[c] = Hc[c];
  }
  fa.prog = prog;
  fa.nlf = nlf; fa.scf = scf; fa.nlb = nl_b; fa.scb = sc_b;
  fa.out3 = out3; fa.out0 = out0;
  void* kp[1] = {(void*)&fa};
  hipLaunchCooperativeKernel((void*)k_fused, dim3(256), dim3(512), kp, 0, stream);

  k_tail<<<48, 256, 0, stream>>>(out3, val, seas, levs, out2, out4, out5);
}

// Round 13
// 676.482 us; speedup vs baseline: 2.2884x; 2.2884x over previous
//
#include <hip/hip_runtime.h>
#include <cstdint>
#include <cstddef>

typedef _Float16 half8 __attribute__((ext_vector_type(8)));
typedef _Float16 half4 __attribute__((ext_vector_type(4)));
typedef float floatx4 __attribute__((ext_vector_type(4)));

namespace {
constexpr int kB = 256, kT = 512, kIN = 48, kOUT = 48, kSEAS = 24, kH = 128;
constexpr int kW = kT - kIN + 1;           // 465 windows
constexpr int kWO = kT - kOUT - kIN + 1;   // 417
constexpr int kNB = kW * kB;               // 119040 rows
constexpr int kMBLK = kNB / 16;            // 7440 row-blocks of 16
constexpr float kLOG2E = 1.44269504088896340736f;
constexpr int kWOBLK = (kWO * kB * 12 + 255) / 256;  // win_out grid chunk
}

#if __has_builtin(__builtin_amdgcn_exp2f)
#define FEXP2(x) __builtin_amdgcn_exp2f(x)
#else
#define FEXP2(x) exp2f(x)
#endif
#if __has_builtin(__builtin_amdgcn_rcpf)
#define FRCP(x) __builtin_amdgcn_rcpf(x)
#else
#define FRCP(x) (1.0f / (x))
#endif

__device__ __forceinline__ float fsig(float y) { return FRCP(1.0f + FEXP2(-y)); }
__device__ __forceinline__ float ftanh(float x) { return 2.0f * fsig(2.0f * kLOG2E * x) - 1.0f; }

// ---------------- ES scan, BLOCKED lag-24; reads train directly ----------------
template <int N>
__device__ __forceinline__ void es_block(int k0, int b, float lev_sm, float omb_l,
                                         float seas_sm, float omb_s, float& lev,
                                         float (&stprev)[kSEAS], const float* __restrict__ trow,
                                         float* __restrict__ seas, float* __restrict__ levs,
                                         float* __restrict__ ratio) {
  float x[N], q[N], lv[N];
#pragma unroll
  for (int jj = 0; jj < N; ++jj) x[jj] = trow[k0 + jj + 1];
#pragma unroll
  for (int jj = 0; jj < N; ++jj) q[jj] = x[jj] * FRCP(stprev[jj]);  // pipelined rcps
#pragma unroll
  for (int jj = 0; jj < N; ++jj) {  // only serial chain: 1 fma per step
    lev = lev_sm * q[jj] + omb_l * lev;
    lv[jj] = lev;
  }
#pragma unroll
  for (int jj = 0; jj < N; ++jj) {
    float sn = seas_sm * (x[jj] * FRCP(lv[jj])) + omb_s * stprev[jj];
    stprev[jj] = sn;
    seas[(k0 + jj + kSEAS + 1) * kB + b] = sn;
    levs[(k0 + jj + 1) * kB + b] = lv[jj];
    ratio[(k0 + jj + 1) * kB + b] = q[jj];
  }
}

__global__ void k_es(const float* __restrict__ train, const float* __restrict__ levp,
                     const float* __restrict__ seasp, const float* __restrict__ inits,
                     float* __restrict__ seas, float* __restrict__ levs,
                     float* __restrict__ ratio) {
  int b = threadIdx.x;
  const float* trow = train + (size_t)b * kT;
  float lev_sm = fsig(levp[0] * kLOG2E);
  float seas_sm = fsig(seasp[0] * kLOG2E);
  float omb_l = 1.0f - lev_sm, omb_s = 1.0f - seas_sm;
  float stprev[kSEAS];
  float s00 = expf(inits[0]);
#pragma unroll
  for (int s = 0; s < kSEAS; ++s) {
    float v = expf(inits[s]);
    seas[s * kB + b] = v;
    if (s >= 1) stprev[s - 1] = v;
  }
  stprev[kSEAS - 1] = s00;
  seas[kSEAS * kB + b] = s00;
  float lev = trow[0] * FRCP(s00);
  levs[b] = lev;
  ratio[b] = lev;
#pragma unroll 1
  for (int blk = 0; blk < 21; ++blk)
    es_block<24>(blk * kSEAS, b, lev_sm, omb_l, seas_sm, omb_s, lev, stprev, trow, seas, levs,
                 ratio);
  es_block<7>(504, b, lev_sm, omb_l, seas_sm, omb_s, lev, stprev, trow, seas, levs, ratio);
  for (int j = 0; j < kOUT - kSEAS; ++j)
    seas[(kT + kSEAS + j) * kB + b] = seas[(kT + j) * kB + b];
}

// ---------------- window build: win_in + win_out in one kernel ----------------
__global__ void k_win(const float* __restrict__ ratio, const float* __restrict__ levs,
                      _Float16* __restrict__ win, float* __restrict__ out1) {
  int w = blockIdx.x;
  int tid = threadIdx.x;
  if (w < kW) {  // win_in: f16, padded K=64
#pragma unroll
    for (int i = 0; i < 16; ++i) {
      int o = i * 256 + tid;
      int b = o >> 3;
      int j0 = (o & 7) * 8;
      half8 h;
      if (j0 < kIN) {
        float rl = FRCP(levs[(kIN - 1 + w) * kB + b]);
#pragma unroll
        for (int jj = 0; jj < 8; ++jj) {
          int j = j0 + jj;
          float v = (j < kIN) ? ratio[(w + j) * kB + b] * rl : 0.0f;
          h[jj] = (_Float16)v;
        }
      } else {
#pragma unroll
        for (int jj = 0; jj < 8; ++jj) h[jj] = (_Float16)0.0f;
      }
      *(half8*)(win + ((size_t)(w * kB + b)) * 64 + j0) = h;
    }
  } else {  // win_out -> out1 (fp32 exact)
    int idx = (w - kW) * 256 + tid;
    if (idx >= kWO * kB * 12) return;
    int row = idx / 12;
    int j0 = (idx - row * 12) * 4;
    int wo = row >> 8;
    int b = row & 255;
    float rl = FRCP(levs[(kIN - 1 + wo) * kB + b]);
    floatx4 v;
#pragma unroll
    for (int jj = 0; jj < 4; ++jj) v[jj] = ratio[(kIN + wo + j0 + jj) * kB + b] * rl;
    *(floatx4*)(out1 + (size_t)row * kOUT + j0) = v;
  }
}

// ---------------- weight prep (single kernel, blockIdx.y = segment; seg14 zeros prog) ----------------
__device__ __forceinline__ void prep_bias_elem(const float* bih, const float* bhh, float* dst,
                                               int c) {
  int ct = c >> 4, n16 = c & 15, g = ct & 3, wv = ct >> 2;
  int row = g * 128 + wv * 16 + n16;
  float sc = (g == 2) ? 2.0f * kLOG2E : kLOG2E;
  dst[c] = (bih[row] + bhh[row]) * sc;
}

__device__ __forceinline__ void prep_frag_elem(const float* Wsrc, _Float16* dst, int KB, int Kreal,
                                               int srcld, int perm, int idx) {
  int jj = idx & 7;
  int lane = (idx >> 3) & 63;
  int kb = (idx >> 9) % KB;
  int ct = idx / (KB * 512);
  int n16 = lane & 15;
  int k = kb * 32 + ((lane >> 4) << 3) + jj;
  int row;
  float sc;
  if (perm) {
    int g = ct & 3, wv = ct >> 2;
    row = g * 128 + wv * 16 + n16;
    sc = (g == 2) ? 2.0f * kLOG2E : kLOG2E;
  } else {
    row = ct * 16 + n16;
    sc = 1.0f;
  }
  float v = (k < Kreal) ? Wsrc[row * srcld + k] * sc : 0.0f;
  dst[idx] = (_Float16)v;
}

struct PrepArgs {
  const float* bih[4];
  const float* bhh[4];
  float* biasp[4];
  const float* wih[4];
  _Float16* wihf[4];
  const float* whh[4];
  _Float16* whhf[4];
  const float* nlw;
  _Float16* nlf;
  const float* scw;
  _Float16* scf;
  int* prog;
};

__global__ void k_prep_all(PrepArgs a) {
  int seg = blockIdx.y;
  int idx = blockIdx.x * 256 + threadIdx.x;
  if (seg < 4) {
    if (idx < 512) prep_bias_elem(a.bih[seg], a.bhh[seg], a.biasp[seg], idx);
  } else if (seg == 4) {
    if (idx < 32 * 2 * 512) prep_frag_elem(a.wih[0], a.wihf[0], 2, 48, 48, 1, idx);
  } else if (seg < 8) {
    int c = seg - 4;
    if (idx < 32 * 4 * 512) prep_frag_elem(a.wih[c], a.wihf[c], 4, 128, 128, 1, idx);
  } else if (seg < 12) {
    int c = seg - 8;
    if (idx < 32 * 4 * 512) prep_frag_elem(a.whh[c], a.whhf[c], 4, 128, 128, 1, idx);
  } else if (seg == 12) {
    if (idx < 8 * 4 * 512) prep_frag_elem(a.nlw, a.nlf, 4, 128, 128, 0, idx);
  } else if (seg == 13) {
    if (idx < 3 * 4 * 512) prep_frag_elem(a.scw, a.scf, 4, 128, 128, 0, idx);
  } else {
    if (idx < 320) a.prog[idx] = 0;
  }
}

// ---------------- fused 4-cell streaming LSTM (R4/R10-exact: best measured ~575 us) ----------------
// 240 WGs: cell0=wg[0,16) d=1; cell1=[16,48) d=2; cell2=[48,112) d=4; cell3=[112,240) d=8.
// All WGs of one ib share an XCD. RELAXED polls + one acquire fence per quantum (8).
struct FArgs {
  const _Float16* win;
  const _Float16* wihf[4];
  const _Float16* whhf[4];
  const float* biasp[4];
  _Float16* H[4];
  int* prog;
};

__device__ __forceinline__ void wait_prog(int* p, int need, int& fenced, int* obs_sh) {
  if (need <= fenced) return;  // uniform condition
  if (threadIdx.x == 0) {
    int v;
    while ((v = __hip_atomic_load(p, __ATOMIC_RELAXED, __HIP_MEMORY_SCOPE_AGENT)) < need)
      __builtin_amdgcn_s_sleep(16);
    *obs_sh = v;
  }
  __syncthreads();
  int v = *obs_sh;
  __builtin_amdgcn_fence(__ATOMIC_ACQUIRE, "agent");  // single buffer_inv
  fenced = v;
}

template <int KXB, bool POLL, bool REL>
__device__ __forceinline__ void floop(const _Float16* __restrict__ Xsrc,
                                      const _Float16* __restrict__ wihp,
                                      const _Float16* __restrict__ whhp,
                                      const float* __restrict__ bp, _Float16* __restrict__ Hout,
                                      int* progIn, int sprev, int* progOut, int d, int kd, int ib,
                                      _Float16 (*hbuf)[2048], int* obs_sh) {
  int tid = threadIdx.x;
  int wv = tid >> 6, lane = tid & 63, m = lane & 15, kq = lane >> 4;
  half8 wxf[4][KXB], whf[4][4];
#pragma unroll
  for (int g = 0; g < 4; ++g) {
#pragma unroll
    for (int kb = 0; kb < KXB; ++kb)
      wxf[g][kb] = *(const half8*)(wihp + ((((wv * 4 + g) * KXB + kb) * 64 + lane) * 8));
#pragma unroll
    for (int kb = 0; kb < 4; ++kb)
      whf[g][kb] = *(const half8*)(whhp + ((((wv * 4 + g) * 4 + kb) * 64 + lane) * 8));
  }
  float bg[4];
#pragma unroll
  for (int g = 0; g < 4; ++g) bg[g] = bp[(wv * 4 + g) * 16 + m];
  float cc[4] = {0.f, 0.f, 0.f, 0.f};
  int nsteps = (kW - kd + d - 1) / d;
  const int xstride = KXB * 32;
  int fenced = 0;
  if (POLL) wait_prog(progIn + (kd & ((1 << sprev) - 1)), (kd >> sprev) + 1, fenced, obs_sh);
  half8 hxc[KXB], hxn[KXB];
  {
    const _Float16* xrow = Xsrc + (size_t)(kd * kB + ib * 16 + m) * xstride + kq * 8;
#pragma unroll
    for (int kb = 0; kb < KXB; ++kb) hxc[kb] = *(const half8*)(xrow + kb * 32);
  }
  for (int j = 0; j < nsteps; ++j) {
    int ph = j & 1;
    int wtn = (j + 1) * d + kd;
    bool havenext = (j + 1 < nsteps);
    if (POLL && havenext)
      wait_prog(progIn + (wtn & ((1 << sprev) - 1)), (wtn >> sprev) + 1, fenced, obs_sh);
    floatx4 acc[4];
#pragma unroll
    for (int g = 0; g < 4; ++g) acc[g] = (floatx4){bg[g], bg[g], bg[g], bg[g]};
    if (havenext) {
      const _Float16* xrow = Xsrc + (size_t)(wtn * kB + ib * 16 + m) * xstride + kq * 8;
#pragma unroll
      for (int kb = 0; kb < KXB; ++kb) hxn[kb] = *(const half8*)(xrow + kb * 32);
    }
#pragma unroll
    for (int kb = 0; kb < KXB; ++kb)
#pragma unroll
      for (int g = 0; g < 4; ++g)
        acc[g] = __builtin_amdgcn_mfma_f32_16x16x32_f16(hxc[kb], wxf[g][kb], acc[g], 0, 0, 0);
    if (j > 0) {
#pragma unroll
      for (int kb = 0; kb < 4; ++kb) {
        int gran = (kb * 4 + kq) ^ m;
        half8 a = *(const half8*)(&hbuf[ph ^ 1][m * 128 + gran * 8]);
#pragma unroll
        for (int g = 0; g < 4; ++g)
          acc[g] = __builtin_amdgcn_mfma_f32_16x16x32_f16(a, whf[g][kb], acc[g], 0, 0, 0);
      }
    }
    _Float16 hv[4];
#pragma unroll
    for (int r = 0; r < 4; ++r) {
      float iv = fsig(acc[0][r]);
      float fv = fsig(acc[1][r]);
      float g2 = fsig(acc[2][r]);
      float ov = fsig(acc[3][r]);
      cc[r] = fv * cc[r] + iv * (2.0f * g2 - 1.0f);
      float tc = 2.0f * fsig(cc[r] * (2.0f * kLOG2E)) - 1.0f;
      hv[r] = (_Float16)(ov * tc);
      int brow = kq * 4 + r;
      int hu = wv * 16 + m;
      int gran = (hu >> 3) ^ brow;
      hbuf[ph][brow * 128 + gran * 8 + (hu & 7)] = hv[r];
    }
    __syncthreads();
    {
      int hu = wv * 16 + m;
      size_t rb = (size_t)((j * d + kd) * kB + ib * 16 + kq * 4);
#pragma unroll
      for (int r = 0; r < 4; ++r) Hout[(rb + r) * kH + hu] = hv[r];
    }
    if (REL && (((j & 7) == 7) || (j + 1 == nsteps))) {
      __syncthreads();  // full drain (vmcnt0): H stores visible before release
      if (tid == 0)
        __hip_atomic_store(progOut, j + 1, __ATOMIC_RELEASE, __HIP_MEMORY_SCOPE_AGENT);
    }
#pragma unroll
    for (int kb = 0; kb < KXB; ++kb) hxc[kb] = hxn[kb];
  }
}

__global__ __launch_bounds__(512) void k_fused(FArgs a) {
  __shared__ _Float16 hbuf[2][2048];
  __shared__ int obs_sh;
  int w = blockIdx.x;
  int cell, d, kd, ib;
  if (w < 16) {
    cell = 0; d = 1; kd = 0; ib = w;
  } else if (w < 48) {
    cell = 1; d = 2; kd = (w - 16) >> 4; ib = (w - 16) & 15;
  } else if (w < 112) {
    cell = 2; d = 4; kd = (w - 48) >> 4; ib = (w - 48) & 15;
  } else {
    cell = 3; d = 8; kd = (w - 112) >> 4; ib = (w - 112) & 15;
  }
  const _Float16* Xsrc = (cell == 0) ? a.win : a.H[cell - 1];
  _Float16* Hout = a.H[cell];
  int* progOut = a.prog + (cell * 16 + ib) * 4 + kd;
  int* progIn = (cell > 0) ? a.prog + ((cell - 1) * 16 + ib) * 4 : nullptr;
  int sprev = (cell == 2) ? 1 : ((cell == 3) ? 2 : 0);
  if (cell == 0)
    floop<2, false, true>(Xsrc, a.wihf[0], a.whhf[0], a.biasp[0], Hout, nullptr, 0, progOut, d,
                          kd, ib, hbuf, &obs_sh);
  else if (cell < 3)
    floop<4, true, true>(Xsrc, a.wihf[cell], a.whhf[cell], a.biasp[cell], Hout, progIn, sprev,
                         progOut, d, kd, ib, hbuf, &obs_sh);
  else
    floop<4, true, false>(Xsrc, a.wihf[3], a.whhf[3], a.biasp[3], Hout, progIn, sprev, progOut,
                          d, kd, ib, hbuf, &obs_sh);
}

// ---------------- fused nl+sc epilogue: U stays in registers/LDS (no U buffer) ----------------
// 930 blocks x 8 waves; wave handles one 16-row mblk. U tile round-trips a private
// swizzled LDS region (wave-coherent: no barriers), then sc GEMM writes out3/out0.
__global__ __launch_bounds__(512) void k_nlsc(const _Float16* __restrict__ H3,
                                              const _Float16* __restrict__ H1,
                                              const _Float16* __restrict__ nlf,
                                              const float* __restrict__ nlb,
                                              const _Float16* __restrict__ scf,
                                              const float* __restrict__ scb,
                                              float* __restrict__ out3,
                                              float* __restrict__ out0) {
  __shared__ _Float16 ubuf[8][2048];
  int tid = threadIdx.x, wv = tid >> 6, lane = tid & 63, m = lane & 15, kq = lane >> 4;
  int mblk = blockIdx.x * 8 + wv;
  const _Float16* r3 = H3 + (size_t)(mblk * 16 + m) * kH + kq * 8;
  const _Float16* r1 = H1 + (size_t)(mblk * 16 + m) * kH + kq * 8;
  half8 af[4];
#pragma unroll
  for (int kb = 0; kb < 4; ++kb) {
    half8 v3 = *(const half8*)(r3 + kb * 32);
    half8 v1 = *(const half8*)(r1 + kb * 32);
    af[kb] = v3 + v1;  // residual add
  }
#pragma unroll
  for (int t0 = 0; t0 < 8; ++t0) {
    float nb = nlb[t0 * 16 + m];
    floatx4 acc = {nb, nb, nb, nb};
#pragma unroll
    for (int kb = 0; kb < 4; ++kb) {
      half8 bf = *(const half8*)(nlf + ((size_t)((t0 * 4 + kb) * 64 + lane)) * 8);
      acc = __builtin_amdgcn_mfma_f32_16x16x32_f16(af[kb], bf, acc, 0, 0, 0);
    }
#pragma unroll
    for (int r = 0; r < 4; ++r) {  // U -> swizzled LDS (same granule XOR as floop)
      int brow = kq * 4 + r, hu = t0 * 16 + m;
      int gran = (hu >> 3) ^ brow;
      ubuf[wv][brow * 128 + gran * 8 + (hu & 7)] = (_Float16)ftanh(acc[r]);
    }
  }
  half8 uf[4];
#pragma unroll
  for (int kb = 0; kb < 4; ++kb) {
    int gran = (kb * 4 + kq) ^ m;
    uf[kb] = *(const half8*)(&ubuf[wv][m * 128 + gran * 8]);
  }
  size_t row = (size_t)mblk * 16 + kq * 4;
#pragma unroll
  for (int ct = 0; ct < 3; ++ct) {
    float sb = scb[ct * 16 + m];
    floatx4 acc = {sb, sb, sb, sb};
#pragma unroll
    for (int kb = 0; kb < 4; ++kb) {
      half8 sf = *(const half8*)(scf + ((size_t)((ct * 4 + kb) * 64 + lane)) * 8);
      acc = __builtin_amdgcn_mfma_f32_16x16x32_f16(uf[kb], sf, acc, 0, 0, 0);
    }
#pragma unroll
    for (int r = 0; r < 4; ++r) {
      size_t rw = row + r;
      float v = acc[r];
      out3[rw * kOUT + ct * 16 + m] = v;
      if (rw < (size_t)kWO * kB) out0[rw * kOUT + ct * 16 + m] = v;
    }
  }
}

// ---------------- tail: outputs 2, 4, 5 ----------------
__global__ void k_tail(const float* __restrict__ out3, const float* __restrict__ val,
                       const float* __restrict__ seas, const float* __restrict__ levs,
                       float* __restrict__ out2, float* __restrict__ out4,
                       float* __restrict__ out5) {
  int idx = blockIdx.x * 256 + threadIdx.x;
  int b = idx / kOUT, j = idx % kOUT;
  float s = seas[(kT + j) * kB + b];
  float L = levs[(kT - 1) * kB + b];
  float net = out3[(size_t)(kW - 1) * kB * kOUT + idx];
  float hp = net * s * L;
  out2[idx] = hp > 0.0f ? hp : 0.0f;
  float v = val[idx];
  out4[idx] = v;
  out5[idx] = v / s / L;
}

extern "C" void kernel_launch(void* const* d_in, const int* in_sizes, int n_in, void* d_out,
                              int out_size, void* d_ws, size_t ws_size, hipStream_t stream) {
  const float* train = (const float*)d_in[0];
  const float* val = (const float*)d_in[1];
  const float* levp = (const float*)d_in[3];
  const float* seasp = (const float*)d_in[4];
  const float* inits = (const float*)d_in[5];
  const float* w_ih[4] = {(const float*)d_in[6], (const float*)d_in[10], (const float*)d_in[14],
                          (const float*)d_in[18]};
  const float* w_hh[4] = {(const float*)d_in[7], (const float*)d_in[11], (const float*)d_in[15],
                          (const float*)d_in[19]};
  const float* b_ih[4] = {(const float*)d_in[8], (const float*)d_in[12], (const float*)d_in[16],
                          (const float*)d_in[20]};
  const float* b_hh[4] = {(const float*)d_in[9], (const float*)d_in[13], (const float*)d_in[17],
                          (const float*)d_in[21]};
  const float* nl_w = (const float*)d_in[22];
  const float* nl_b = (const float*)d_in[23];
  const float* sc_w = (const float*)d_in[24];
  const float* sc_b = (const float*)d_in[25];

  char* wsb = (char*)d_ws;
  size_t off = 0;
  auto alloc = [&](size_t bytes) -> void* {
    void* p = wsb + off;
    off = (off + bytes + 255) & ~(size_t)255;
    return p;
  };
  float* seas = (float*)alloc((size_t)560 * kB * 4);
  float* levs = (float*)alloc((size_t)kT * kB * 4);
  float* ratio = (float*)alloc((size_t)kT * kB * 4);
  _Float16* win = (_Float16*)alloc((size_t)kNB * 64 * 2);
  _Float16* Hc[4];
  for (int c = 0; c < 4; ++c) Hc[c] = (_Float16*)alloc((size_t)kNB * kH * 2);
  float* biasp[4];
  for (int c = 0; c < 4; ++c) biasp[c] = (float*)alloc(512 * 4);
  _Float16* wihf[4];
  wihf[0] = (_Float16*)alloc((size_t)32 * 2 * 512 * 2);
  for (int c = 1; c < 4; ++c) wihf[c] = (_Float16*)alloc((size_t)32 * 4 * 512 * 2);
  _Float16* whhf[4];
  for (int c = 0; c < 4; ++c) whhf[c] = (_Float16*)alloc((size_t)32 * 4 * 512 * 2);
  _Float16* nlf = (_Float16*)alloc((size_t)8 * 4 * 512 * 2);
  _Float16* scf = (_Float16*)alloc((size_t)3 * 4 * 512 * 2);
  int* prog = (int*)alloc(320 * 4);

  float* out0 = (float*)d_out;
  float* out1 = out0 + (size_t)kWO * kB * kOUT;
  float* out2 = out1 + (size_t)kWO * kB * kOUT;
  float* out3 = out2 + (size_t)kB * kOUT;
  float* out4 = out3 + (size_t)kW * kB * kOUT;
  float* out5 = out4 + (size_t)kB * kOUT;

  k_es<<<1, kB, 0, stream>>>(train, levp, seasp, inits, seas, levs, ratio);
  k_win<<<kW + kWOBLK, kB, 0, stream>>>(ratio, levs, win, out1);

  PrepArgs pa;
  for (int c = 0; c < 4; ++c) {
    pa.bih[c] = b_ih[c]; pa.bhh[c] = b_hh[c]; pa.biasp[c] = biasp[c];
    pa.wih[c] = w_ih[c]; pa.wihf[c] = wihf[c];
    pa.whh[c] = w_hh[c]; pa.whhf[c] = whhf[c];
  }
  pa.nlw = nl_w; pa.nlf = nlf; pa.scw = sc_w; pa.scf = scf; pa.prog = prog;
  k_prep_all<<<dim3(256, 15), 256, 0, stream>>>(pa);

  FArgs fa;
  fa.win = win;
  for (int c = 0; c < 4; ++c) {
    fa.wihf[c] = wihf[c]; fa.whhf[c] = whhf[c]; fa.biasp[c] = biasp[c]; fa.H[c] = Hc[c];
  }
  fa.prog = prog;
  void* kp[1] = {(void*)&fa};
  hipLaunchCooperativeKernel((void*)k_fused, dim3(240), dim3(512), kp, 0, stream);

  // nl+sc fused epilogue (U never hits HBM)
  k_nlsc<<<kMBLK / 8, 512, 0, stream>>>(Hc[3], Hc[1], nlf, nl_b, scf, sc_b, out3, out0);
  k_tail<<<48, 256, 0, stream>>>(out3, val, seas, levs, out2, out4, out5);
}